// Round 2
// baseline (270.743 us; speedup 1.0000x reference)
//
#include <hip/hip_runtime.h>

// Problem constants
#define B_  4
#define S_  2048
#define D_  1024
#define H_  16
#define DH_ 64
#define M_  (B_*S_)   // 8192

typedef __bf16 bf8_t __attribute__((ext_vector_type(8)));
typedef float f4_t __attribute__((ext_vector_type(4)));
typedef unsigned short u16x8_t __attribute__((ext_vector_type(8)));

static __device__ __forceinline__ unsigned short f2bf(float f) {
  return __builtin_bit_cast(unsigned short, (__bf16)f);
}
static __device__ __forceinline__ bf8_t ldbf8(const unsigned short* p) {
  return __builtin_bit_cast(bf8_t, *(const u16x8_t*)p);
}
// pack two f32 -> (bf16(b)<<16)|bf16(a): single VOP3 cvt_pk (RNE), was 3 VALU.
static __device__ __forceinline__ unsigned int pkbf(float a, float b) {
  unsigned int r;
  asm("v_cvt_pk_bf16_f32 %0, %1, %2" : "=v"(r) : "v"(a), "v"(b));
  return r;
}
#define MFMA16(a,b,c) __builtin_amdgcn_mfma_f32_16x16x32_bf16((a),(b),(c),0,0,0)
#define GLDS16(gp, lp) __builtin_amdgcn_global_load_lds( \
    (const __attribute__((address_space(1))) void*)(gp), \
    (__attribute__((address_space(3))) void*)(lp), 16, 0, 0)

// 0.125 (1/sqrt(dh)) * log2(e): folded into Q so softmax uses bare exp2.
#define QSCALE 0.18033688011112042f

// ---------------- fused convert kernel ----------------
// blocks [0,8192): x->bf16 (coalesced both sides)
// blocks [8192,8576): Wq/Wk/Wv -> Wcat^T via LDS tile (64dh x 128k per block)
// blocks [8576,8640): Wo -> Wot^T via LDS tile (128x128)

__global__ void cvt_all(const float* __restrict__ x,
                        const float* __restrict__ Wq, const float* __restrict__ Wk,
                        const float* __restrict__ Wv, const float* __restrict__ Wo,
                        unsigned short* __restrict__ xb, unsigned short* __restrict__ Wcat,
                        unsigned short* __restrict__ Wot) {
  __shared__ unsigned short T[128 * 130];             // 33.3 KB, used by transpose parts
  const int blk = blockIdx.x, tid = threadIdx.x;
  if (blk < 8192) {
    int i = blk * 256 + tid;                          // over M_*D_/4
    float4 v = ((const float4*)x)[i];
    unsigned int lo = f2bf(v.x) | ((unsigned int)f2bf(v.y) << 16);
    unsigned int hi = f2bf(v.z) | ((unsigned int)f2bf(v.w) << 16);
    ((uint2*)xb)[i] = make_uint2(lo, hi);
  } else if (blk < 8576) {
    // W (H,D,DH) slab: qkv/h from bid>>3, k-chunk 128 from bid&7.
    int bid = blk - 8192;
    int qh = bid >> 3, kc = bid & 7;
    int qkv = qh >> 4, h = qh & 15;
    const float* W = (qkv == 0) ? Wq : (qkv == 1 ? Wk : Wv);
    const float* src = W + (size_t)h * 65536 + (size_t)kc * 128 * 64;
    // load 128k x 64dh coalesced -> T[k][dh] (pad 66)
#pragma unroll
    for (int jj = 0; jj < 32; jj++) {
      int idx = jj * 256 + tid;                       // kl = idx>>6, dh = idx&63
      T[(idx >> 6) * 66 + (idx & 63)] = f2bf(src[idx]);
    }
    __syncthreads();
    // gather columns -> coalesced 16B writes: Wcat[n0+dh][kc*128 + k]
    int n0 = qkv * 1024 + h * 64;
#pragma unroll
    for (int it = 0; it < 4; it++) {
      int u = it * 256 + tid;                         // 0..1023
      int dh = u >> 4, k8 = (u & 15) * 8;
      unsigned short v[8];
#pragma unroll
      for (int ii = 0; ii < 8; ii++) v[ii] = T[(k8 + ii) * 66 + dh];
      *(u16x8_t*)&Wcat[(size_t)(n0 + dh) * 1024 + kc * 128 + k8] =
          *(const u16x8_t*)v;
    }
  } else {
    // Wo (D,D) row-major -> Wot[n][k]; 128x128 tile
    int bid = blk - 8576;
    int r0 = (bid >> 3) * 128, c0 = (bid & 7) * 128;  // r0: k-dim, c0: n-dim
#pragma unroll
    for (int jj = 0; jj < 64; jj++) {
      int idx = jj * 256 + tid;                       // i = idx>>7, j = idx&127
      int i = idx >> 7, j = idx & 127;
      T[i * 130 + j] = f2bf(Wo[(size_t)(r0 + i) * 1024 + c0 + j]);
    }
    __syncthreads();
#pragma unroll
    for (int it = 0; it < 8; it++) {
      int u = it * 256 + tid;                         // 0..2047
      int j = u >> 4, i8 = (u & 15) * 8;
      unsigned short v[8];
#pragma unroll
      for (int ii = 0; ii < 8; ii++) v[ii] = T[(i8 + ii) * 130 + j];
      *(u16x8_t*)&Wot[(size_t)(c0 + j) * 1024 + r0 + i8] = *(const u16x8_t*)v;
    }
  }
}

// ---------------- GEMM core (128x128 tile, BK=32, K=1024, B^T input) ----------------

static __device__ __forceinline__ void gemm_core(const unsigned short* __restrict__ A,
    const unsigned short* __restrict__ Bt, unsigned short* As, unsigned short* Bs,
    int bm, int bn, f4_t acc[4][4])
{
  const int tid = threadIdx.x, w = tid >> 6, lane = tid & 63;
  const int quad = lane >> 4, col = lane & 15;
  const int wm = (w >> 1) * 64, wn = (w & 1) * 64;
  const int srow = lane >> 2;                         // 0..15
  const int goff = (((lane & 3) ^ ((srow >> 1) & 3)) * 8);
  const unsigned short* ga = A  + (size_t)(bm + 32 * w + srow) * D_ + goff;
  const unsigned short* gb = Bt + (size_t)(bn + 32 * w + srow) * D_ + goff;
  unsigned short* lAs0 = &As[(32 * w) * 32];
  unsigned short* lAs1 = &As[(32 * w + 16) * 32];
  unsigned short* lBs0 = &Bs[(32 * w) * 32];
  unsigned short* lBs1 = &Bs[(32 * w + 16) * 32];
  const int psw = (quad ^ ((col >> 1) & 3)) * 8;

  for (int k0 = 0; k0 < D_; k0 += 32) {
    __syncthreads();
    GLDS16(ga + k0,           lAs0);
    GLDS16(ga + 16 * D_ + k0, lAs1);
    GLDS16(gb + k0,           lBs0);
    GLDS16(gb + 16 * D_ + k0, lBs1);
    __syncthreads();
    bf8_t af[4], bfv[4];
#pragma unroll
    for (int mt = 0; mt < 4; mt++) af[mt]  = ldbf8(&As[(wm + 16 * mt + col) * 32 + psw]);
#pragma unroll
    for (int nt = 0; nt < 4; nt++) bfv[nt] = ldbf8(&Bs[(wn + 16 * nt + col) * 32 + psw]);
#pragma unroll
    for (int mt = 0; mt < 4; mt++)
#pragma unroll
      for (int nt = 0; nt < 4; nt++)
        acc[mt][nt] = MFMA16(af[mt], bfv[nt], acc[mt][nt]);
  }
}

// ---------------- stage 1: QKV projection ----------------
// qkv type is uniform per block (bn strip of 128). Q/K epilogue goes through a
// 32x128 LDS tile (4 passes) -> fully coalesced 16B/lane stores. V keeps the
// direct 8B s-contiguous store (already r-contiguous).
// R2: XCD-chunked bijective block swizzle (T1): nwg=1536, 192 blocks/XCD ->
// each XCD touches 8 A-strips (2MB, L2-resident) instead of all 16MB.

__global__ __launch_bounds__(256, 3) void gemm_qkv(const unsigned short* __restrict__ A,
    const unsigned short* __restrict__ Bt,
    unsigned short* __restrict__ Qp, unsigned short* __restrict__ Kp,
    unsigned short* __restrict__ Vtp)
{
  __shared__ __align__(16) unsigned short As[128 * 32];
  __shared__ __align__(16) unsigned short Bs[128 * 32];
  __shared__ __align__(16) unsigned short Cs[32 * 136];   // 8.7 KB epilogue tile
  f4_t acc[4][4] = {};
  // grid is dim3(24, 64): lin id x-fastest matches HW dispatch order.
  const int lin = blockIdx.y * 24 + blockIdx.x;           // 0..1535
  const int nid = (lin & 7) * 192 + (lin >> 3);           // bijective (1536 % 8 == 0)
  const int bm = (nid / 24) * 128, bn = (nid % 24) * 128;
  gemm_core(A, Bt, As, Bs, bm, bn, acc);

  const int tid = threadIdx.x, w = tid >> 6, lane = tid & 63;
  const int quad = lane >> 4, col = lane & 15;
  const int wn = (w & 1) * 64;
  const int qkv = bn >> 10;

  if (qkv == 2) {
    const int wm = (w >> 1) * 64;
#pragma unroll
    for (int nt = 0; nt < 4; nt++) {
      int n = bn + wn + 16 * nt + col;
      int r1 = n & 1023, h = r1 >> 6, dh = r1 & 63;
#pragma unroll
      for (int mt = 0; mt < 4; mt++) {
        int m0 = bm + wm + 16 * mt + quad * 4;
        int b = m0 >> 11, s0 = m0 & 2047;
        unsigned int lo = f2bf(acc[mt][nt][0]) | ((unsigned int)f2bf(acc[mt][nt][1]) << 16);
        unsigned int hi = f2bf(acc[mt][nt][2]) | ((unsigned int)f2bf(acc[mt][nt][3]) << 16);
        *(uint2*)&Vtp[((size_t)(b * H_ + h) * DH_ + dh) * S_ + s0] = make_uint2(lo, hi);
      }
    }
    return;
  }

  const float qs = (qkv == 0) ? QSCALE : 1.0f;
  unsigned short* dst = (qkv == 0) ? Qp : Kp;
  const int h0 = (bn & 1023) >> 6;                    // this strip covers heads h0, h0+1
#pragma unroll
  for (int p = 0; p < 4; p++) {
    __syncthreads();
    if ((w >> 1) == (p >> 1)) {                       // 2 waves store rows [32p,32p+32)
#pragma unroll
      for (int mi = 0; mi < 2; mi++) {
        int mt = 2 * (p & 1) + mi;
        int lr0 = mi * 16 + quad * 4;
#pragma unroll
        for (int nt = 0; nt < 4; nt++) {
          int n = wn + nt * 16 + col;
#pragma unroll
          for (int r = 0; r < 4; r++)
            Cs[(lr0 + r) * 136 + n] = f2bf(acc[mt][nt][r] * qs);
        }
      }
    }
    __syncthreads();
#pragma unroll
    for (int it = 0; it < 2; it++) {
      int u = it * 256 + tid;                         // 0..511
      int lr = u >> 4, kk8 = u & 15;
      u16x8_t v = *(const u16x8_t*)&Cs[lr * 136 + kk8 * 8];
      int g = bm + 32 * p + lr;
      int b = g >> 11, s = g & 2047;
      int h = h0 + (kk8 >> 3), dh0 = (kk8 & 7) * 8;
      *(u16x8_t*)&dst[((size_t)(b * H_ + h) * S_ + s) * DH_ + dh0] = v;
    }
  }
}

// ---------------- stage 2: flash attention, S^T formulation ----------------
// grid(bh, qt): all 16 q-tiles of a head share blockIdx.x%8 -> same XCD L2.
// S^T = MFMA(K_frag, Q_frag): C row = sk (r-contiguous), col = q.
// R1 restructure (T3-min/T4/T5): KVBLK 64, Ks/Vs double-buffered; stage(next)
// issued before compute(cur); raw s_barrier + counted vmcnt(4) keeps prefetch
// in flight across the barrier. s_setprio(1) wraps MFMA clusters.
// R2: pkbf is now a single v_cvt_pk_bf16_f32 (was 3 VALU/pair) -> -64 VALU
// insts per wave-tile in the softmax pack.

__global__ __launch_bounds__(256, 4) void flash_attn(const unsigned short* __restrict__ Qp,
    const unsigned short* __restrict__ Kp, const unsigned short* __restrict__ Vtp,
    unsigned short* __restrict__ Cc)
{
  __shared__ __align__(16) unsigned short Ks[2][64 * 64];   // 2 x 8 KB
  __shared__ __align__(16) unsigned short Vs[2][64 * 64];   // 2 x 8 KB
  __shared__ __align__(16) unsigned short Ps[4][32 * 32];   // 8 KB
  const int tid = threadIdx.x, w = tid >> 6, lane = tid & 63;
  const int quad = lane >> 4, col = lane & 15;
  const int bh = blockIdx.x, qt = blockIdx.y;

  // Q fragments straight from global (row = lane&15, k contiguous); pre-scaled.
  const unsigned short* Qg = Qp + ((size_t)bh * S_ + qt * 128 + w * 32) * DH_;
  bf8_t aq[2][2];
#pragma unroll
  for (int t = 0; t < 2; t++)
#pragma unroll
    for (int kc = 0; kc < 2; kc++)
      aq[t][kc] = ldbf8(Qg + (t * 16 + col) * DH_ + kc * 32 + quad * 8);

  const bf8_t vones = __builtin_bit_cast(bf8_t, (u16x8_t)((unsigned short)0x3F80));
  f4_t o[2][4] = {};
  f4_t lacc[2] = {};                                  // l in o-row layout via ones-MFMA

  const unsigned short* Kg0 = Kp  + (size_t)bh * S_ * DH_;
  const unsigned short* Vg0 = Vtp + (size_t)bh * DH_ * S_;
  unsigned short* Pw = &Ps[w][0];
  const int psw_f = (col >> 1) & 3;                   // Ps swizzle f(q)

  // staging geometry: wave w owns rows [16w,16w+16) of each 64-row tile,
  // two GLDS of 8 rows each. row&7 == lane>>3 for every GLDS -> shared swizzle.
  const int rl8 = lane >> 3;                          // 0..7
  const int sw8 = ((lane & 7) ^ rl8) * 8;             // source pre-swizzle (shorts)
  const unsigned short* KgW = Kg0 + (size_t)(16 * w + rl8) * DH_ + sw8;
  const unsigned short* VgW = Vg0 + (size_t)(16 * w + rl8) * S_ + sw8;

  auto stage = [&](int t, int bsel) {
    const unsigned short* Kg = KgW + (size_t)t * 64 * DH_;
    const unsigned short* Vg = VgW + t * 64;
    unsigned short* KsB = &Ks[bsel][(16 * w) * 64];
    unsigned short* VsB = &Vs[bsel][(16 * w) * 64];
    GLDS16(Kg,                  KsB);
    GLDS16(Kg + 8 * DH_,        KsB + 8 * 64);
    GLDS16(Vg,                  VsB);
    GLDS16(Vg + (size_t)8 * S_, VsB + 8 * 64);
  };

  // per-tile compute: two independent 32-col quarters
  auto compute_tile = [&](const unsigned short* KsC, const unsigned short* VsC) {
#pragma unroll
    for (int hh = 0; hh < 2; hh++) {
      f4_t sc[2][2] = {};                             // S^T: row=sk_local, col=q
      __builtin_amdgcn_s_setprio(1);
#pragma unroll
      for (int ctl = 0; ctl < 2; ctl++) {
        int krow = (hh * 2 + ctl) * 16 + col;
#pragma unroll
        for (int kc = 0; kc < 2; kc++) {
          bf8_t bk = ldbf8(&KsC[krow * 64 + (((kc * 4 + quad) ^ (krow & 7)) * 8)]);
          sc[0][ctl] = MFMA16(bk, aq[0][kc], sc[0][ctl]);   // operand order: S^T
          sc[1][ctl] = MFMA16(bk, aq[1][kc], sc[1][ctl]);
        }
      }
      __builtin_amdgcn_s_setprio(0);

      // exp2 + cvt_pk pack + b64 store into Ps[q][sk] (granule ^ f(q) swizzle)
#pragma unroll
      for (int t = 0; t < 2; t++)
#pragma unroll
        for (int ctl = 0; ctl < 2; ctl++) {
          float p0 = __builtin_amdgcn_exp2f(sc[t][ctl][0]);
          float p1 = __builtin_amdgcn_exp2f(sc[t][ctl][1]);
          float p2 = __builtin_amdgcn_exp2f(sc[t][ctl][2]);
          float p3 = __builtin_amdgcn_exp2f(sc[t][ctl][3]);
          unsigned int d0 = pkbf(p0, p1);
          unsigned int d1 = pkbf(p2, p3);
          int g = ctl * 2 + (quad >> 1);              // sk granule 0..3 within quarter
          unsigned short* pdst = &Pw[(t * 16 + col) * 32 + ((g ^ psw_f) << 3) + (quad & 1) * 4];
          *(uint2*)pdst = make_uint2(d0, d1);
        }

      // PV: one K=32 step per quarter
      {
        __builtin_amdgcn_s_setprio(1);
        bf8_t ap0 = ldbf8(&Pw[(0 * 16 + col) * 32 + ((quad ^ psw_f) << 3)]);
        bf8_t ap1 = ldbf8(&Pw[(1 * 16 + col) * 32 + ((quad ^ psw_f) << 3)]);
        lacc[0] = MFMA16(ap0, vones, lacc[0]);
        lacc[1] = MFMA16(ap1, vones, lacc[1]);
        int gk = hh * 4 + quad;                       // Vs sk granule 0..7
#pragma unroll
        for (int cv = 0; cv < 4; cv++) {
          int vr = cv * 16 + col;
          bf8_t bv = ldbf8(&VsC[vr * 64 + ((gk ^ (vr & 7)) * 8)]);
          o[0][cv] = MFMA16(ap0, bv, o[0][cv]);
          o[1][cv] = MFMA16(ap1, bv, o[1][cv]);
        }
        __builtin_amdgcn_s_setprio(0);
      }
    }
  };

  // pipeline: prologue stage(0); per iter: stage(next) -> vmcnt(4) -> barrier
  // -> compute(cur) -> barrier. Last tile drains with vmcnt(0).
  stage(0, 0);
#pragma unroll 2
  for (int kt = 0; kt < S_ / 64 - 1; kt++) {
    stage(kt + 1, (kt + 1) & 1);
    asm volatile("s_waitcnt vmcnt(4)" ::: "memory");
    __builtin_amdgcn_s_barrier();
    compute_tile(&Ks[kt & 1][0], &Vs[kt & 1][0]);
    __builtin_amdgcn_s_barrier();
  }
  asm volatile("s_waitcnt vmcnt(0)" ::: "memory");
  __builtin_amdgcn_s_barrier();
  compute_tile(&Ks[1][0], &Vs[1][0]);                 // tile 31 sits in buffer 1

  // epilogue: O/l -> concat (b, s, h*64+dh) bf16; lacc rows match o rows exactly.
  const int b = bh >> 4, h = bh & 15;
#pragma unroll
  for (int t = 0; t < 2; t++) {
    float linv[4];
#pragma unroll
    for (int r = 0; r < 4; r++)
      linv[r] = 1.0f / lacc[t][r];
#pragma unroll
    for (int cv = 0; cv < 4; cv++)
#pragma unroll
      for (int r = 0; r < 4; r++) {
        float v = o[t][cv][r] * linv[r];
        int s = qt * 128 + w * 32 + t * 16 + quad * 4 + r;
        int dcol = h * 64 + cv * 16 + col;
        Cc[((size_t)b * S_ + s) * D_ + dcol] = f2bf(v);
      }
  }
}

// ---------------- stage 3: output projection ----------------
// f32 epilogue via 32x128 LDS tile -> 16B/lane coalesced stores.
// R2: XCD-chunked bijective block swizzle (T1): nwg=512, 64 blocks/XCD.

__global__ __launch_bounds__(256, 3) void gemm_out(const unsigned short* __restrict__ A,
    const unsigned short* __restrict__ Bt, float* __restrict__ Out)
{
  __shared__ __align__(16) unsigned short As[128 * 32];
  __shared__ __align__(16) unsigned short Bs[128 * 32];
  __shared__ __align__(16) float Cf[32 * 132];            // 16.9 KB epilogue tile
  f4_t acc[4][4] = {};
  const int lin = blockIdx.y * 8 + blockIdx.x;            // 0..511, x-fastest
  const int nid = (lin & 7) * 64 + (lin >> 3);            // bijective (512 % 8 == 0)
  const int bm = (nid >> 3) * 128, bn = (nid & 7) * 128;
  gemm_core(A, Bt, As, Bs, bm, bn, acc);

  const int tid = threadIdx.x, w = tid >> 6, lane = tid & 63;
  const int quad = lane >> 4, col = lane & 15;
  const int wn = (w & 1) * 64;
#pragma unroll
  for (int p = 0; p < 4; p++) {
    __syncthreads();
    if ((w >> 1) == (p >> 1)) {
#pragma unroll
      for (int mi = 0; mi < 2; mi++) {
        int mt = 2 * (p & 1) + mi;
        int lr0 = mi * 16 + quad * 4;
#pragma unroll
        for (int nt = 0; nt < 4; nt++) {
          int n = wn + nt * 16 + col;
#pragma unroll
          for (int r = 0; r < 4; r++)
            Cf[(lr0 + r) * 132 + n] = acc[mt][nt][r];
        }
      }
    }
    __syncthreads();
#pragma unroll
    for (int it = 0; it < 4; it++) {
      int u = it * 256 + tid;                         // 0..1023
      int lr = u >> 5, kk4 = u & 31;
      f4_t v = *(const f4_t*)&Cf[lr * 132 + kk4 * 4];
      int g = bm + 32 * p + lr;
      *(f4_t*)&Out[(size_t)g * D_ + bn + kk4 * 4] = v;
    }
  }
}

// ---------------- launch ----------------

extern "C" void kernel_launch(void* const* d_in, const int* in_sizes, int n_in,
                              void* d_out, int out_size, void* d_ws, size_t ws_size,
                              hipStream_t stream) {
  const float* x  = (const float*)d_in[0];
  const float* Wq = (const float*)d_in[1];
  const float* Wk = (const float*)d_in[2];
  const float* Wv = (const float*)d_in[3];
  const float* Wo = (const float*)d_in[4];
  float* out = (float*)d_out;

  char* ws = (char*)d_ws;
  size_t off = 0;
  auto alloc = [&](size_t bytes) -> void* {
    void* p = ws + off;
    off += (bytes + 255) & ~(size_t)255;
    return p;
  };
  unsigned short* xb   = (unsigned short*)alloc((size_t)M_ * D_ * 2);       // 16 MB
  unsigned short* Wcat = (unsigned short*)alloc((size_t)3 * D_ * D_ * 2);   // 6 MB
  unsigned short* Wot  = (unsigned short*)alloc((size_t)D_ * D_ * 2);       // 2 MB
  unsigned short* Qb   = (unsigned short*)alloc((size_t)B_ * H_ * S_ * DH_ * 2); // 16 MB
  unsigned short* Kb   = (unsigned short*)alloc((size_t)B_ * H_ * S_ * DH_ * 2); // 16 MB
  unsigned short* Vtb  = (unsigned short*)alloc((size_t)B_ * H_ * S_ * DH_ * 2); // 16 MB
  unsigned short* Cc   = (unsigned short*)alloc((size_t)M_ * D_ * 2);       // 16 MB

  cvt_all<<<8640, 256, 0, stream>>>(x, Wq, Wk, Wv, Wo, xb, Wcat, Wot);
  gemm_qkv<<<dim3(3 * D_ / 128, M_ / 128), 256, 0, stream>>>(xb, Wcat, Qb, Kb, Vtb);
  flash_attn<<<dim3(B_ * H_, S_ / 128), 256, 0, stream>>>(Qb, Kb, Vtb, Cc);
  gemm_out<<<dim3(D_ / 128, M_ / 128), 256, 0, stream>>>(Cc, Wot, out);
}

// Round 3
// 265.882 us; speedup vs baseline: 1.0183x; 1.0183x over previous
//
#include <hip/hip_runtime.h>

// Problem constants
#define B_  4
#define S_  2048
#define D_  1024
#define H_  16
#define DH_ 64
#define M_  (B_*S_)   // 8192

typedef __bf16 bf8_t __attribute__((ext_vector_type(8)));
typedef float f4_t __attribute__((ext_vector_type(4)));
typedef unsigned short u16x8_t __attribute__((ext_vector_type(8)));

static __device__ __forceinline__ unsigned short f2bf(float f) {
  return __builtin_bit_cast(unsigned short, (__bf16)f);
}
static __device__ __forceinline__ bf8_t ldbf8(const unsigned short* p) {
  return __builtin_bit_cast(bf8_t, *(const u16x8_t*)p);
}
// pack two f32 -> (bf16(b)<<16)|bf16(a): single VOP3 cvt_pk (RNE)
static __device__ __forceinline__ unsigned int pkbf(float a, float b) {
  unsigned int r;
  asm("v_cvt_pk_bf16_f32 %0, %1, %2" : "=v"(r) : "v"(a), "v"(b));
  return r;
}
#define MFMA16(a,b,c) __builtin_amdgcn_mfma_f32_16x16x32_bf16((a),(b),(c),0,0,0)
#define GLDS16(gp, lp) __builtin_amdgcn_global_load_lds( \
    (const __attribute__((address_space(1))) void*)(gp), \
    (__attribute__((address_space(3))) void*)(lp), 16, 0, 0)

// 0.125 (1/sqrt(dh)) * log2(e): folded into Q so softmax uses bare exp2.
#define QSCALE 0.18033688011112042f

// ---------------- fused convert kernel ----------------
// blocks [0,8192): x->bf16 (coalesced both sides)
// blocks [8192,8576): Wq/Wk/Wv -> Wcat^T via LDS tile (64dh x 128k per block)
// blocks [8576,8640): Wo -> Wot^T via LDS tile (128x128)

__global__ void cvt_all(const float* __restrict__ x,
                        const float* __restrict__ Wq, const float* __restrict__ Wk,
                        const float* __restrict__ Wv, const float* __restrict__ Wo,
                        unsigned short* __restrict__ xb, unsigned short* __restrict__ Wcat,
                        unsigned short* __restrict__ Wot) {
  __shared__ unsigned short T[128 * 130];             // 33.3 KB, used by transpose parts
  const int blk = blockIdx.x, tid = threadIdx.x;
  if (blk < 8192) {
    int i = blk * 256 + tid;                          // over M_*D_/4
    float4 v = ((const float4*)x)[i];
    unsigned int lo = f2bf(v.x) | ((unsigned int)f2bf(v.y) << 16);
    unsigned int hi = f2bf(v.z) | ((unsigned int)f2bf(v.w) << 16);
    ((uint2*)xb)[i] = make_uint2(lo, hi);
  } else if (blk < 8576) {
    // W (H,D,DH) slab: qkv/h from bid>>3, k-chunk 128 from bid&7.
    int bid = blk - 8192;
    int qh = bid >> 3, kc = bid & 7;
    int qkv = qh >> 4, h = qh & 15;
    const float* W = (qkv == 0) ? Wq : (qkv == 1 ? Wk : Wv);
    const float* src = W + (size_t)h * 65536 + (size_t)kc * 128 * 64;
    // load 128k x 64dh coalesced -> T[k][dh] (pad 66)
#pragma unroll
    for (int jj = 0; jj < 32; jj++) {
      int idx = jj * 256 + tid;                       // kl = idx>>6, dh = idx&63
      T[(idx >> 6) * 66 + (idx & 63)] = f2bf(src[idx]);
    }
    __syncthreads();
    // gather columns -> coalesced 16B writes: Wcat[n0+dh][kc*128 + k]
    int n0 = qkv * 1024 + h * 64;
#pragma unroll
    for (int it = 0; it < 4; it++) {
      int u = it * 256 + tid;                         // 0..1023
      int dh = u >> 4, k8 = (u & 15) * 8;
      unsigned short v[8];
#pragma unroll
      for (int ii = 0; ii < 8; ii++) v[ii] = T[(k8 + ii) * 66 + dh];
      *(u16x8_t*)&Wcat[(size_t)(n0 + dh) * 1024 + kc * 128 + k8] =
          *(const u16x8_t*)v;
    }
  } else {
    // Wo (D,D) row-major -> Wot[n][k]; 128x128 tile
    int bid = blk - 8576;
    int r0 = (bid >> 3) * 128, c0 = (bid & 7) * 128;  // r0: k-dim, c0: n-dim
#pragma unroll
    for (int jj = 0; jj < 64; jj++) {
      int idx = jj * 256 + tid;                       // i = idx>>7, j = idx&127
      int i = idx >> 7, j = idx & 127;
      T[i * 130 + j] = f2bf(Wo[(size_t)(r0 + i) * 1024 + c0 + j]);
    }
    __syncthreads();
#pragma unroll
    for (int it = 0; it < 8; it++) {
      int u = it * 256 + tid;                         // 0..2047
      int j = u >> 4, i8 = (u & 15) * 8;
      unsigned short v[8];
#pragma unroll
      for (int ii = 0; ii < 8; ii++) v[ii] = T[(i8 + ii) * 130 + j];
      *(u16x8_t*)&Wot[(size_t)(c0 + j) * 1024 + r0 + i8] = *(const u16x8_t*)v;
    }
  }
}

// ---------------- GEMM core (128x128 tile, BK=32, K=1024, B^T input) ----------------
// (kept for gemm_out; gemm_qkv now uses the 256x256 8-wave 4-phase core below)

static __device__ __forceinline__ void gemm_core(const unsigned short* __restrict__ A,
    const unsigned short* __restrict__ Bt, unsigned short* As, unsigned short* Bs,
    int bm, int bn, f4_t acc[4][4])
{
  const int tid = threadIdx.x, w = tid >> 6, lane = tid & 63;
  const int quad = lane >> 4, col = lane & 15;
  const int wm = (w >> 1) * 64, wn = (w & 1) * 64;
  const int srow = lane >> 2;                         // 0..15
  const int goff = (((lane & 3) ^ ((srow >> 1) & 3)) * 8);
  const unsigned short* ga = A  + (size_t)(bm + 32 * w + srow) * D_ + goff;
  const unsigned short* gb = Bt + (size_t)(bn + 32 * w + srow) * D_ + goff;
  unsigned short* lAs0 = &As[(32 * w) * 32];
  unsigned short* lAs1 = &As[(32 * w + 16) * 32];
  unsigned short* lBs0 = &Bs[(32 * w) * 32];
  unsigned short* lBs1 = &Bs[(32 * w + 16) * 32];
  const int psw = (quad ^ ((col >> 1) & 3)) * 8;

  for (int k0 = 0; k0 < D_; k0 += 32) {
    __syncthreads();
    GLDS16(ga + k0,           lAs0);
    GLDS16(ga + 16 * D_ + k0, lAs1);
    GLDS16(gb + k0,           lBs0);
    GLDS16(gb + 16 * D_ + k0, lBs1);
    __syncthreads();
    bf8_t af[4], bfv[4];
#pragma unroll
    for (int mt = 0; mt < 4; mt++) af[mt]  = ldbf8(&As[(wm + 16 * mt + col) * 32 + psw]);
#pragma unroll
    for (int nt = 0; nt < 4; nt++) bfv[nt] = ldbf8(&Bs[(wn + 16 * nt + col) * 32 + psw]);
#pragma unroll
    for (int mt = 0; mt < 4; mt++)
#pragma unroll
      for (int nt = 0; nt < 4; nt++)
        acc[mt][nt] = MFMA16(af[mt], bfv[nt], acc[mt][nt]);
  }
}

// ---------------- stage 1: QKV projection, 256^2 8-wave 4-phase core ----------------
// R3 rewrite (T2+T3+T4+T5): BM=BN=256, BK=64, 512 threads (8 waves, 2M x 4N;
// wave output 128x64 = acc[8][4]). LDS 128 KB: A,B x dbuf x [2 ks][256 rows][32 k]
// slabs (16 KB each). k-slice slabs keep global_load_lds destinations LINEAR
// while staging at half-tile granularity.
// Swizzle pair (verified in gemm_core): source k-group (lane&3)^((lane>>3)&3),
// read k-group quad^((col>>1)&3) -> 8 lanes per 16B bank-slot, optimal.
// Schedule per K-tile t (buffer b=t&1, staging t+1 into b^1):
//   p0: dsr A[m0..3,ks0]+B[ks0](8) | stage A-ks0(t+1) | bar,lgkm0,16 MFMA,bar
//   p1: dsr A[m4..7,ks0](4)        | stage B-ks0(t+1) | vmcnt(4),bar,...,bar
//   p2: dsr A[m0..3,ks1]+B[ks1](8) | stage A-ks1(t+1) | bar,...,bar
//   p3: dsr A[m4..7,ks1](4)        | stage B-ks1(t+1) | vmcnt(4),bar,...,bar
// Queue sim (2 loads/stage): steady 4-8 in flight; each vmcnt(4) retires
// exactly the k-slice needed 2-4 phases after issue. Never drains to 0.

__global__ __launch_bounds__(512, 2) void gemm_qkv(const unsigned short* __restrict__ A,
    const unsigned short* __restrict__ Bt,
    unsigned short* __restrict__ Qp, unsigned short* __restrict__ Kp,
    unsigned short* __restrict__ Vtp)
{
  __shared__ __align__(16) unsigned short SM[65536];      // 128 KB
  const int tid = threadIdx.x, w = tid >> 6, lane = tid & 63;
  const int quad = lane >> 4, col = lane & 15;
  const int wm = w >> 2, wn = w & 3;
  const int bn = blockIdx.x * 256, bm = blockIdx.y * 256;

  f4_t acc[8][4] = {};

  // staging lane geometry: row = j*128 + w*16 + (lane>>2), k-group pos = lane&3
  const int srow = w * 16 + (lane >> 2);
  const int skoff = ((lane & 3) ^ ((lane >> 3) & 3)) * 8;
  const unsigned short* gA = A  + (size_t)(bm + srow) * D_ + skoff;
  const unsigned short* gB = Bt + (size_t)(bn + srow) * D_ + skoff;
  const int sdst = w * 16 * 32;                           // wave-uniform LDS base

  // read-side frag offsets (shorts). A slab at 0, B slab at 32768; +buf*16384.
  const int rswz = (quad ^ ((col >> 1) & 3)) * 8;
  const int aoff = (wm * 128 + col) * 32 + rswz;          // + ks*8192 + mi*512
  const int boff = (wn * 64 + col) * 32 + rswz;           // + ks*8192 + ni*512

  auto stage_half = [&](int op, int ks, int kt) {         // 2 x GLDS16
    const unsigned short* g = (op ? gB : gA) + (size_t)kt * 64 + ks * 32;
    unsigned short* d = &SM[op * 32768 + (kt & 1) * 16384 + ks * 8192 + sdst];
    GLDS16(g, d);
    GLDS16(g + (size_t)128 * D_, d + 4096);
  };
  bf8_t af[4], bv[4];
  auto ldA = [&](int buf, int ks, int mb) {
    const unsigned short* p = &SM[buf * 16384 + ks * 8192 + aoff + mb * 512];
#pragma unroll
    for (int mi = 0; mi < 4; mi++) af[mi] = ldbf8(p + mi * 512);
  };
  auto ldB = [&](int buf, int ks) {
    const unsigned short* p = &SM[32768 + buf * 16384 + ks * 8192 + boff];
#pragma unroll
    for (int ni = 0; ni < 4; ni++) bv[ni] = ldbf8(p + ni * 512);
  };
  auto mfma16x = [&](int mb) {
#pragma unroll
    for (int mi = 0; mi < 4; mi++)
#pragma unroll
      for (int ni = 0; ni < 4; ni++)
        acc[mb + mi][ni] = MFMA16(af[mi], bv[ni], acc[mb + mi][ni]);
  };

  // prologue: stage all 4 halves of tile 0; wait ks0 landed.
  stage_half(0, 0, 0); stage_half(1, 0, 0); stage_half(0, 1, 0); stage_half(1, 1, 0);
  asm volatile("s_waitcnt vmcnt(4)" ::: "memory");
  __builtin_amdgcn_s_barrier();

  for (int t = 0; t < 15; t++) {
    const int b = t & 1;
    // p0
    ldA(b, 0, 0); ldB(b, 0);
    stage_half(0, 0, t + 1);
    __builtin_amdgcn_s_barrier();
    asm volatile("s_waitcnt lgkmcnt(0)" ::: "memory");
    __builtin_amdgcn_sched_barrier(0);
    __builtin_amdgcn_s_setprio(1); mfma16x(0); __builtin_amdgcn_s_setprio(0);
    __builtin_amdgcn_s_barrier();
    // p1
    ldA(b, 0, 4);
    stage_half(1, 0, t + 1);
    asm volatile("s_waitcnt vmcnt(4)" ::: "memory");   // ks1(t) landed
    __builtin_amdgcn_s_barrier();
    asm volatile("s_waitcnt lgkmcnt(0)" ::: "memory");
    __builtin_amdgcn_sched_barrier(0);
    __builtin_amdgcn_s_setprio(1); mfma16x(4); __builtin_amdgcn_s_setprio(0);
    __builtin_amdgcn_s_barrier();
    // p2
    ldA(b, 1, 0); ldB(b, 1);
    stage_half(0, 1, t + 1);
    __builtin_amdgcn_s_barrier();
    asm volatile("s_waitcnt lgkmcnt(0)" ::: "memory");
    __builtin_amdgcn_sched_barrier(0);
    __builtin_amdgcn_s_setprio(1); mfma16x(0); __builtin_amdgcn_s_setprio(0);
    __builtin_amdgcn_s_barrier();
    // p3
    ldA(b, 1, 4);
    stage_half(1, 1, t + 1);
    asm volatile("s_waitcnt vmcnt(4)" ::: "memory");   // ks0(t+1) landed
    __builtin_amdgcn_s_barrier();
    asm volatile("s_waitcnt lgkmcnt(0)" ::: "memory");
    __builtin_amdgcn_sched_barrier(0);
    __builtin_amdgcn_s_setprio(1); mfma16x(4); __builtin_amdgcn_s_setprio(0);
    __builtin_amdgcn_s_barrier();
  }
  // t = 15 (buffer 1), no staging; ks0 already ensured by t14 p3's vmcnt(4).
  ldA(1, 0, 0); ldB(1, 0);
  asm volatile("s_waitcnt vmcnt(0)" ::: "memory");      // ks1(15) landed
  __builtin_amdgcn_s_barrier();
  mfma16x(0);
  ldA(1, 0, 4); mfma16x(4);
  ldA(1, 1, 0); ldB(1, 1); mfma16x(0);
  ldA(1, 1, 4); mfma16x(4);

  // ---------------- epilogue ----------------
  const int qkv = bn >> 10;                              // 256-tile within one of Q/K/V
  if (qkv == 2) {
    // V: direct 8B s-contiguous stores (r-contiguous rows)
#pragma unroll
    for (int ni = 0; ni < 4; ni++) {
      int n = bn + wn * 64 + ni * 16 + col;
      int r1 = n & 1023, h = r1 >> 6, dh = r1 & 63;
#pragma unroll
      for (int mi = 0; mi < 8; mi++) {
        int m0 = bm + wm * 128 + mi * 16 + quad * 4;
        int b2 = m0 >> 11, s0 = m0 & 2047;
        unsigned int lo = pkbf(acc[mi][ni][0], acc[mi][ni][1]);
        unsigned int hi = pkbf(acc[mi][ni][2], acc[mi][ni][3]);
        *(uint2*)&Vtp[((size_t)(b2 * H_ + h) * DH_ + dh) * S_ + s0] = make_uint2(lo, hi);
      }
    }
    return;
  }

  const float qs = (qkv == 0) ? QSCALE : 1.0f;
  unsigned short* dst = (qkv == 0) ? Qp : Kp;
  const int h0 = (bn & 1023) >> 6;                       // heads h0..h0+3
  unsigned short* Cs = SM;                               // [2 stripes][32][264]
#pragma unroll
  for (int q = 0; q < 4; q++) {
    __syncthreads();
    // wave (wm,wn) writes rows wm*128+q*32..+32, cols wn*64..+64
#pragma unroll
    for (int mi2 = 0; mi2 < 2; mi2++) {
      int mi = q * 2 + mi2;
      int lr0 = mi2 * 16 + quad * 4;
#pragma unroll
      for (int ni = 0; ni < 4; ni++) {
        int c = wn * 64 + ni * 16 + col;
#pragma unroll
        for (int r = 0; r < 4; r++)
          Cs[wm * 8448 + (lr0 + r) * 264 + c] = f2bf(acc[mi][ni][r] * qs);
      }
    }
    __syncthreads();
    // cooperative 16B stores: 2 stripes x 32 rows x 32 col-groups
#pragma unroll
    for (int it = 0; it < 4; it++) {
      int u = it * 512 + tid;                            // 0..2047
      int stripe = u >> 10, v = u & 1023;
      int lr = v >> 5, c8 = v & 31;
      u16x8_t vv = *(const u16x8_t*)&Cs[stripe * 8448 + lr * 264 + c8 * 8];
      int g = bm + stripe * 128 + q * 32 + lr;
      int b2 = g >> 11, s = g & 2047;
      int h = h0 + (c8 >> 3), dh0 = (c8 & 7) * 8;
      *(u16x8_t*)&dst[((size_t)(b2 * H_ + h) * S_ + s) * DH_ + dh0] = vv;
    }
  }
}

// ---------------- stage 2: flash attention, S^T formulation ----------------
// grid(bh, qt): all 16 q-tiles of a head share blockIdx.x%8 -> same XCD L2.
// KVBLK 64, Ks/Vs double-buffered; stage(next) before compute(cur); raw
// s_barrier + counted vmcnt(4). setprio(1) wraps MFMA clusters. cvt_pk pack.

__global__ __launch_bounds__(256, 4) void flash_attn(const unsigned short* __restrict__ Qp,
    const unsigned short* __restrict__ Kp, const unsigned short* __restrict__ Vtp,
    unsigned short* __restrict__ Cc)
{
  __shared__ __align__(16) unsigned short Ks[2][64 * 64];   // 2 x 8 KB
  __shared__ __align__(16) unsigned short Vs[2][64 * 64];   // 2 x 8 KB
  __shared__ __align__(16) unsigned short Ps[4][32 * 32];   // 8 KB
  const int tid = threadIdx.x, w = tid >> 6, lane = tid & 63;
  const int quad = lane >> 4, col = lane & 15;
  const int bh = blockIdx.x, qt = blockIdx.y;

  const unsigned short* Qg = Qp + ((size_t)bh * S_ + qt * 128 + w * 32) * DH_;
  bf8_t aq[2][2];
#pragma unroll
  for (int t = 0; t < 2; t++)
#pragma unroll
    for (int kc = 0; kc < 2; kc++)
      aq[t][kc] = ldbf8(Qg + (t * 16 + col) * DH_ + kc * 32 + quad * 8);

  const bf8_t vones = __builtin_bit_cast(bf8_t, (u16x8_t)((unsigned short)0x3F80));
  f4_t o[2][4] = {};
  f4_t lacc[2] = {};

  const unsigned short* Kg0 = Kp  + (size_t)bh * S_ * DH_;
  const unsigned short* Vg0 = Vtp + (size_t)bh * DH_ * S_;
  unsigned short* Pw = &Ps[w][0];
  const int psw_f = (col >> 1) & 3;

  const int rl8 = lane >> 3;
  const int sw8 = ((lane & 7) ^ rl8) * 8;
  const unsigned short* KgW = Kg0 + (size_t)(16 * w + rl8) * DH_ + sw8;
  const unsigned short* VgW = Vg0 + (size_t)(16 * w + rl8) * S_ + sw8;

  auto stage = [&](int t, int bsel) {
    const unsigned short* Kg = KgW + (size_t)t * 64 * DH_;
    const unsigned short* Vg = VgW + t * 64;
    unsigned short* KsB = &Ks[bsel][(16 * w) * 64];
    unsigned short* VsB = &Vs[bsel][(16 * w) * 64];
    GLDS16(Kg,                  KsB);
    GLDS16(Kg + 8 * DH_,        KsB + 8 * 64);
    GLDS16(Vg,                  VsB);
    GLDS16(Vg + (size_t)8 * S_, VsB + 8 * 64);
  };

  auto compute_tile = [&](const unsigned short* KsC, const unsigned short* VsC) {
#pragma unroll
    for (int hh = 0; hh < 2; hh++) {
      f4_t sc[2][2] = {};
      __builtin_amdgcn_s_setprio(1);
#pragma unroll
      for (int ctl = 0; ctl < 2; ctl++) {
        int krow = (hh * 2 + ctl) * 16 + col;
#pragma unroll
        for (int kc = 0; kc < 2; kc++) {
          bf8_t bk = ldbf8(&KsC[krow * 64 + (((kc * 4 + quad) ^ (krow & 7)) * 8)]);
          sc[0][ctl] = MFMA16(bk, aq[0][kc], sc[0][ctl]);
          sc[1][ctl] = MFMA16(bk, aq[1][kc], sc[1][ctl]);
        }
      }
      __builtin_amdgcn_s_setprio(0);

#pragma unroll
      for (int t = 0; t < 2; t++)
#pragma unroll
        for (int ctl = 0; ctl < 2; ctl++) {
          float p0 = __builtin_amdgcn_exp2f(sc[t][ctl][0]);
          float p1 = __builtin_amdgcn_exp2f(sc[t][ctl][1]);
          float p2 = __builtin_amdgcn_exp2f(sc[t][ctl][2]);
          float p3 = __builtin_amdgcn_exp2f(sc[t][ctl][3]);
          unsigned int d0 = pkbf(p0, p1);
          unsigned int d1 = pkbf(p2, p3);
          int g = ctl * 2 + (quad >> 1);
          unsigned short* pdst = &Pw[(t * 16 + col) * 32 + ((g ^ psw_f) << 3) + (quad & 1) * 4];
          *(uint2*)pdst = make_uint2(d0, d1);
        }

      {
        __builtin_amdgcn_s_setprio(1);
        bf8_t ap0 = ldbf8(&Pw[(0 * 16 + col) * 32 + ((quad ^ psw_f) << 3)]);
        bf8_t ap1 = ldbf8(&Pw[(1 * 16 + col) * 32 + ((quad ^ psw_f) << 3)]);
        lacc[0] = MFMA16(ap0, vones, lacc[0]);
        lacc[1] = MFMA16(ap1, vones, lacc[1]);
        int gk = hh * 4 + quad;
#pragma unroll
        for (int cv = 0; cv < 4; cv++) {
          int vr = cv * 16 + col;
          bf8_t bv = ldbf8(&VsC[vr * 64 + ((gk ^ (vr & 7)) * 8)]);
          o[0][cv] = MFMA16(ap0, bv, o[0][cv]);
          o[1][cv] = MFMA16(ap1, bv, o[1][cv]);
        }
        __builtin_amdgcn_s_setprio(0);
      }
    }
  };

  stage(0, 0);
#pragma unroll 2
  for (int kt = 0; kt < S_ / 64 - 1; kt++) {
    stage(kt + 1, (kt + 1) & 1);
    asm volatile("s_waitcnt vmcnt(4)" ::: "memory");
    __builtin_amdgcn_s_barrier();
    compute_tile(&Ks[kt & 1][0], &Vs[kt & 1][0]);
    __builtin_amdgcn_s_barrier();
  }
  asm volatile("s_waitcnt vmcnt(0)" ::: "memory");
  __builtin_amdgcn_s_barrier();
  compute_tile(&Ks[1][0], &Vs[1][0]);

  const int b = bh >> 4, h = bh & 15;
#pragma unroll
  for (int t = 0; t < 2; t++) {
    float linv[4];
#pragma unroll
    for (int r = 0; r < 4; r++)
      linv[r] = 1.0f / lacc[t][r];
#pragma unroll
    for (int cv = 0; cv < 4; cv++)
#pragma unroll
      for (int r = 0; r < 4; r++) {
        float v = o[t][cv][r] * linv[r];
        int s = qt * 128 + w * 32 + t * 16 + quad * 4 + r;
        int dcol = h * 64 + cv * 16 + col;
        Cc[((size_t)b * S_ + s) * D_ + dcol] = f2bf(v);
      }
  }
}

// ---------------- stage 3: output projection ----------------
// f32 epilogue via 32x128 LDS tile -> 16B/lane coalesced stores.
// R3: XCD swizzle reverted (R2 evidence: regressed; GEMMs are L2-resident).

__global__ __launch_bounds__(256, 3) void gemm_out(const unsigned short* __restrict__ A,
    const unsigned short* __restrict__ Bt, float* __restrict__ Out)
{
  __shared__ __align__(16) unsigned short As[128 * 32];
  __shared__ __align__(16) unsigned short Bs[128 * 32];
  __shared__ __align__(16) float Cf[32 * 132];            // 16.9 KB epilogue tile
  f4_t acc[4][4] = {};
  const int bm = blockIdx.y * 128, bn = blockIdx.x * 128;
  gemm_core(A, Bt, As, Bs, bm, bn, acc);

  const int tid = threadIdx.x, w = tid >> 6, lane = tid & 63;
  const int quad = lane >> 4, col = lane & 15;
  const int wn = (w & 1) * 64;
#pragma unroll
  for (int p = 0; p < 4; p++) {
    __syncthreads();
    if ((w >> 1) == (p >> 1)) {
#pragma unroll
      for (int mi = 0; mi < 2; mi++) {
        int mt = 2 * (p & 1) + mi;
        int lr0 = mi * 16 + quad * 4;
#pragma unroll
        for (int nt = 0; nt < 4; nt++) {
          int n = wn + nt * 16 + col;
#pragma unroll
          for (int r = 0; r < 4; r++)
            Cf[(lr0 + r) * 132 + n] = acc[mt][nt][r];
        }
      }
    }
    __syncthreads();
#pragma unroll
    for (int it = 0; it < 4; it++) {
      int u = it * 256 + tid;                         // 0..1023
      int lr = u >> 5, kk4 = u & 31;
      f4_t v = *(const f4_t*)&Cf[lr * 132 + kk4 * 4];
      int g = bm + 32 * p + lr;
      *(f4_t*)&Out[(size_t)g * D_ + bn + kk4 * 4] = v;
    }
  }
}

// ---------------- launch ----------------

extern "C" void kernel_launch(void* const* d_in, const int* in_sizes, int n_in,
                              void* d_out, int out_size, void* d_ws, size_t ws_size,
                              hipStream_t stream) {
  const float* x  = (const float*)d_in[0];
  const float* Wq = (const float*)d_in[1];
  const float* Wk = (const float*)d_in[2];
  const float* Wv = (const float*)d_in[3];
  const float* Wo = (const float*)d_in[4];
  float* out = (float*)d_out;

  char* ws = (char*)d_ws;
  size_t off = 0;
  auto alloc = [&](size_t bytes) -> void* {
    void* p = ws + off;
    off += (bytes + 255) & ~(size_t)255;
    return p;
  };
  unsigned short* xb   = (unsigned short*)alloc((size_t)M_ * D_ * 2);       // 16 MB
  unsigned short* Wcat = (unsigned short*)alloc((size_t)3 * D_ * D_ * 2);   // 6 MB
  unsigned short* Wot  = (unsigned short*)alloc((size_t)D_ * D_ * 2);       // 2 MB
  unsigned short* Qb   = (unsigned short*)alloc((size_t)B_ * H_ * S_ * DH_ * 2); // 16 MB
  unsigned short* Kb   = (unsigned short*)alloc((size_t)B_ * H_ * S_ * DH_ * 2); // 16 MB
  unsigned short* Vtb  = (unsigned short*)alloc((size_t)B_ * H_ * S_ * DH_ * 2); // 16 MB
  unsigned short* Cc   = (unsigned short*)alloc((size_t)M_ * D_ * 2);       // 16 MB

  cvt_all<<<8640, 256, 0, stream>>>(x, Wq, Wk, Wv, Wo, xb, Wcat, Wot);
  gemm_qkv<<<dim3(3 * D_ / 256, M_ / 256), 512, 0, stream>>>(xb, Wcat, Qb, Kb, Vtb);
  flash_attn<<<dim3(B_ * H_, S_ / 128), 256, 0, stream>>>(Qb, Kb, Vtb, Cc);
  gemm_out<<<dim3(D_ / 128, M_ / 128), 256, 0, stream>>>(Cc, Wot, out);
}

// Round 5
// 256.890 us; speedup vs baseline: 1.0539x; 1.0350x over previous
//
#include <hip/hip_runtime.h>

// Problem constants
#define B_  4
#define S_  2048
#define D_  1024
#define H_  16
#define DH_ 64
#define M_  (B_*S_)   // 8192

typedef __bf16 bf8_t __attribute__((ext_vector_type(8)));
typedef float f4_t __attribute__((ext_vector_type(4)));
typedef unsigned short u16x8_t __attribute__((ext_vector_type(8)));
typedef unsigned int u32x4_t __attribute__((ext_vector_type(4)));

static __device__ __forceinline__ unsigned short f2bf(float f) {
  return __builtin_bit_cast(unsigned short, (__bf16)f);
}
static __device__ __forceinline__ bf8_t ldbf8(const unsigned short* p) {
  return __builtin_bit_cast(bf8_t, *(const u16x8_t*)p);
}
// pack two f32 -> (bf16(b)<<16)|bf16(a): single VOP3 cvt_pk (RNE)
static __device__ __forceinline__ unsigned int pkbf(float a, float b) {
  unsigned int r;
  asm("v_cvt_pk_bf16_f32 %0, %1, %2" : "=v"(r) : "v"(a), "v"(b));
  return r;
}
#define MFMA16(a,b,c) __builtin_amdgcn_mfma_f32_16x16x32_bf16((a),(b),(c),0,0,0)
#define GLDS16(gp, lp) __builtin_amdgcn_global_load_lds( \
    (const __attribute__((address_space(1))) void*)(gp), \
    (__attribute__((address_space(3))) void*)(lp), 16, 0, 0)

// 0.125 (1/sqrt(dh)) * log2(e): folded into Q so softmax uses bare exp2.
#define QSCALE 0.18033688011112042f

// ---------------- fused convert kernel ----------------
// blocks [0,8192): x->bf16 (coalesced both sides)
// blocks [8192,8576): Wq/Wk/Wv -> Wcat^T via LDS tile (64dh x 128k per block)
// blocks [8576,8640): Wo -> Wot^T via LDS tile (128x128)

__global__ void cvt_all(const float* __restrict__ x,
                        const float* __restrict__ Wq, const float* __restrict__ Wk,
                        const float* __restrict__ Wv, const float* __restrict__ Wo,
                        unsigned short* __restrict__ xb, unsigned short* __restrict__ Wcat,
                        unsigned short* __restrict__ Wot) {
  __shared__ unsigned short T[128 * 130];             // 33.3 KB, used by transpose parts
  const int blk = blockIdx.x, tid = threadIdx.x;
  if (blk < 8192) {
    int i = blk * 256 + tid;                          // over M_*D_/4
    float4 v = ((const float4*)x)[i];
    unsigned int lo = f2bf(v.x) | ((unsigned int)f2bf(v.y) << 16);
    unsigned int hi = f2bf(v.z) | ((unsigned int)f2bf(v.w) << 16);
    ((uint2*)xb)[i] = make_uint2(lo, hi);
  } else if (blk < 8576) {
    // W (H,D,DH) slab: qkv/h from bid>>3, k-chunk 128 from bid&7.
    int bid = blk - 8192;
    int qh = bid >> 3, kc = bid & 7;
    int qkv = qh >> 4, h = qh & 15;
    const float* W = (qkv == 0) ? Wq : (qkv == 1 ? Wk : Wv);
    const float* src = W + (size_t)h * 65536 + (size_t)kc * 128 * 64;
    // load 128k x 64dh coalesced -> T[k][dh] (pad 66)
#pragma unroll
    for (int jj = 0; jj < 32; jj++) {
      int idx = jj * 256 + tid;                       // kl = idx>>6, dh = idx&63
      T[(idx >> 6) * 66 + (idx & 63)] = f2bf(src[idx]);
    }
    __syncthreads();
    // gather columns -> coalesced 16B writes: Wcat[n0+dh][kc*128 + k]
    int n0 = qkv * 1024 + h * 64;
#pragma unroll
    for (int it = 0; it < 4; it++) {
      int u = it * 256 + tid;                         // 0..1023
      int dh = u >> 4, k8 = (u & 15) * 8;
      unsigned short v[8];
#pragma unroll
      for (int ii = 0; ii < 8; ii++) v[ii] = T[(k8 + ii) * 66 + dh];
      *(u16x8_t*)&Wcat[(size_t)(n0 + dh) * 1024 + kc * 128 + k8] =
          *(const u16x8_t*)v;
    }
  } else {
    // Wo (D,D) row-major -> Wot[n][k]; 128x128 tile
    int bid = blk - 8576;
    int r0 = (bid >> 3) * 128, c0 = (bid & 7) * 128;  // r0: k-dim, c0: n-dim
#pragma unroll
    for (int jj = 0; jj < 64; jj++) {
      int idx = jj * 256 + tid;                       // i = idx>>7, j = idx&127
      int i = idx >> 7, j = idx & 127;
      T[i * 130 + j] = f2bf(Wo[(size_t)(r0 + i) * 1024 + c0 + j]);
    }
    __syncthreads();
#pragma unroll
    for (int it = 0; it < 8; it++) {
      int u = it * 256 + tid;                         // 0..2047
      int j = u >> 4, i8 = (u & 15) * 8;
      unsigned short v[8];
#pragma unroll
      for (int ii = 0; ii < 8; ii++) v[ii] = T[(i8 + ii) * 130 + j];
      *(u16x8_t*)&Wot[(size_t)(c0 + j) * 1024 + r0 + i8] = *(const u16x8_t*)v;
    }
  }
}

// ---------------- GEMM core (128x128 tile, BK=32, K=1024, B^T input) ----------------

static __device__ __forceinline__ void gemm_core(const unsigned short* __restrict__ A,
    const unsigned short* __restrict__ Bt, unsigned short* As, unsigned short* Bs,
    int bm, int bn, f4_t acc[4][4])
{
  const int tid = threadIdx.x, w = tid >> 6, lane = tid & 63;
  const int quad = lane >> 4, col = lane & 15;
  const int wm = (w >> 1) * 64, wn = (w & 1) * 64;
  const int srow = lane >> 2;                         // 0..15
  const int goff = (((lane & 3) ^ ((srow >> 1) & 3)) * 8);
  const unsigned short* ga = A  + (size_t)(bm + 32 * w + srow) * D_ + goff;
  const unsigned short* gb = Bt + (size_t)(bn + 32 * w + srow) * D_ + goff;
  unsigned short* lAs0 = &As[(32 * w) * 32];
  unsigned short* lAs1 = &As[(32 * w + 16) * 32];
  unsigned short* lBs0 = &Bs[(32 * w) * 32];
  unsigned short* lBs1 = &Bs[(32 * w + 16) * 32];
  const int psw = (quad ^ ((col >> 1) & 3)) * 8;

  for (int k0 = 0; k0 < D_; k0 += 32) {
    __syncthreads();
    GLDS16(ga + k0,           lAs0);
    GLDS16(ga + 16 * D_ + k0, lAs1);
    GLDS16(gb + k0,           lBs0);
    GLDS16(gb + 16 * D_ + k0, lBs1);
    __syncthreads();
    bf8_t af[4], bfv[4];
#pragma unroll
    for (int mt = 0; mt < 4; mt++) af[mt]  = ldbf8(&As[(wm + 16 * mt + col) * 32 + psw]);
#pragma unroll
    for (int nt = 0; nt < 4; nt++) bfv[nt] = ldbf8(&Bs[(wn + 16 * nt + col) * 32 + psw]);
#pragma unroll
    for (int mt = 0; mt < 4; mt++)
#pragma unroll
      for (int nt = 0; nt < 4; nt++)
        acc[mt][nt] = MFMA16(af[mt], bfv[nt], acc[mt][nt]);
  }
}

// ---------------- stage 1: QKV projection (128^2 version, known-good) --------

__global__ __launch_bounds__(256, 3) void gemm_qkv(const unsigned short* __restrict__ A,
    const unsigned short* __restrict__ Bt,
    unsigned short* __restrict__ Qp, unsigned short* __restrict__ Kp,
    unsigned short* __restrict__ Vtp)
{
  __shared__ __align__(16) unsigned short As[128 * 32];
  __shared__ __align__(16) unsigned short Bs[128 * 32];
  __shared__ __align__(16) unsigned short Cs[32 * 136];   // 8.7 KB epilogue tile
  f4_t acc[4][4] = {};
  const int bm = blockIdx.y * 128, bn = blockIdx.x * 128;
  gemm_core(A, Bt, As, Bs, bm, bn, acc);

  const int tid = threadIdx.x, w = tid >> 6, lane = tid & 63;
  const int quad = lane >> 4, col = lane & 15;
  const int wn = (w & 1) * 64;
  const int qkv = bn >> 10;

  if (qkv == 2) {
    const int wm = (w >> 1) * 64;
#pragma unroll
    for (int nt = 0; nt < 4; nt++) {
      int n = bn + wn + 16 * nt + col;
      int r1 = n & 1023, h = r1 >> 6, dh = r1 & 63;
#pragma unroll
      for (int mt = 0; mt < 4; mt++) {
        int m0 = bm + wm + 16 * mt + quad * 4;
        int b = m0 >> 11, s0 = m0 & 2047;
        unsigned int lo = f2bf(acc[mt][nt][0]) | ((unsigned int)f2bf(acc[mt][nt][1]) << 16);
        unsigned int hi = f2bf(acc[mt][nt][2]) | ((unsigned int)f2bf(acc[mt][nt][3]) << 16);
        *(uint2*)&Vtp[((size_t)(b * H_ + h) * DH_ + dh) * S_ + s0] = make_uint2(lo, hi);
      }
    }
    return;
  }

  const float qs = (qkv == 0) ? QSCALE : 1.0f;
  unsigned short* dst = (qkv == 0) ? Qp : Kp;
  const int h0 = (bn & 1023) >> 6;                    // this strip covers heads h0, h0+1
#pragma unroll
  for (int p = 0; p < 4; p++) {
    __syncthreads();
    if ((w >> 1) == (p >> 1)) {                       // 2 waves store rows [32p,32p+32)
#pragma unroll
      for (int mi = 0; mi < 2; mi++) {
        int mt = 2 * (p & 1) + mi;
        int lr0 = mi * 16 + quad * 4;
#pragma unroll
        for (int nt = 0; nt < 4; nt++) {
          int n = wn + nt * 16 + col;
#pragma unroll
          for (int r = 0; r < 4; r++)
            Cs[(lr0 + r) * 136 + n] = f2bf(acc[mt][nt][r] * qs);
        }
      }
    }
    __syncthreads();
#pragma unroll
    for (int it = 0; it < 2; it++) {
      int u = it * 256 + tid;                         // 0..511
      int lr = u >> 4, kk8 = u & 15;
      u16x8_t v = *(const u16x8_t*)&Cs[lr * 136 + kk8 * 8];
      int g = bm + 32 * p + lr;
      int b = g >> 11, s = g & 2047;
      int h = h0 + (kk8 >> 3), dh0 = (kk8 & 7) * 8;
      *(u16x8_t*)&dst[((size_t)(b * H_ + h) * S_ + s) * DH_ + dh0] = v;
    }
  }
}

// ---------------- stage 2: flash attention, S^T formulation ----------------
// grid(bh, qt): all 16 q-tiles of a head share blockIdx.x%8 -> same XCD L2.
// KVBLK 64, Ks/Vs double-buffered; stage(next) before compute(cur); raw
// s_barrier + counted vmcnt(4); setprio around MFMA clusters; cvt_pk pack.
// R5: P never touches LDS OR cross-lane ops. The QK^T A-row -> K-row map is
// free to choose, so pick krow = hh*32 + (col>>2)*8 + ctl*4 + (col&3):
// then sc[t][ctl][r] = P[sk = hh*32 + quad*8 + ctl*4 + r][q = t*16+col], and
// the 4 cvt_pk words per t are EXACTLY the PV A-fragment (element e of ap[t]
// <-> sk = hh*32 + quad*8 + e). l-sum and PV are permutation-invariant per q.
// K-read bank math: krow&7 has bit2 wave-uniform (ctl), so the K stage
// swizzle becomes f(row) = (row&3)|((row>>3)&1)<<2; read XORs f(krow) =
// (col&3)|((col>>2)&1)<<2 -> 8 lanes per 16B slot, conflict-free.

__global__ __launch_bounds__(256, 4) void flash_attn(const unsigned short* __restrict__ Qp,
    const unsigned short* __restrict__ Kp, const unsigned short* __restrict__ Vtp,
    unsigned short* __restrict__ Cc)
{
  __shared__ __align__(16) unsigned short Ks[2][64 * 64];   // 2 x 8 KB
  __shared__ __align__(16) unsigned short Vs[2][64 * 64];   // 2 x 8 KB
  const int tid = threadIdx.x, w = tid >> 6, lane = tid & 63;
  const int quad = lane >> 4, col = lane & 15;
  const int bh = blockIdx.x, qt = blockIdx.y;

  const unsigned short* Qg = Qp + ((size_t)bh * S_ + qt * 128 + w * 32) * DH_;
  bf8_t aq[2][2];
#pragma unroll
  for (int t = 0; t < 2; t++)
#pragma unroll
    for (int kc = 0; kc < 2; kc++)
      aq[t][kc] = ldbf8(Qg + (t * 16 + col) * DH_ + kc * 32 + quad * 8);

  const bf8_t vones = __builtin_bit_cast(bf8_t, (u16x8_t)((unsigned short)0x3F80));
  f4_t o[2][4] = {};
  f4_t lacc[2] = {};

  const unsigned short* Kg0 = Kp  + (size_t)bh * S_ * DH_;
  const unsigned short* Vg0 = Vtp + (size_t)bh * DH_ * S_;

  const int rl8 = lane >> 3;                          // 0..7
  const int g8  = lane & 7;
  // K staging swizzle f(row) = (row&3)|((row>>3)&1)<<2; rows 16w+8jj+rl8:
  // row&3 = rl8&3, (row>>3)&1 = jj.
  const int ksw0 = (g8 ^ (rl8 & 3)) * 8;
  const int ksw1 = (g8 ^ ((rl8 & 3) | 4)) * 8;
  // V staging swizzle f(row) = row&7 = rl8 (unchanged).
  const int vsw  = (g8 ^ rl8) * 8;
  const unsigned short* KgW = Kg0 + (size_t)(16 * w + rl8) * DH_;
  const unsigned short* VgW = Vg0 + (size_t)(16 * w + rl8) * S_ + vsw;

  auto stage = [&](int t, int bsel) {
    const unsigned short* Kg = KgW + (size_t)t * 64 * DH_;
    const unsigned short* Vg = VgW + t * 64;
    unsigned short* KsB = &Ks[bsel][(16 * w) * 64];
    unsigned short* VsB = &Vs[bsel][(16 * w) * 64];
    GLDS16(Kg + ksw0,           KsB);
    GLDS16(Kg + 8 * DH_ + ksw1, KsB + 8 * 64);
    GLDS16(Vg,                  VsB);
    GLDS16(Vg + (size_t)8 * S_, VsB + 8 * 64);
  };

  auto compute_tile = [&](const unsigned short* KsC, const unsigned short* VsC) {
#pragma unroll
    for (int hh = 0; hh < 2; hh++) {
      f4_t sc[2][2] = {};
      __builtin_amdgcn_s_setprio(1);
#pragma unroll
      for (int ctl = 0; ctl < 2; ctl++) {
        // permuted A-row -> K-row map (see header comment)
        int krow = hh * 32 + (col >> 2) * 8 + ctl * 4 + (col & 3);
        int fk = (col & 3) | (((col >> 2) & 1) << 2);
#pragma unroll
        for (int kc = 0; kc < 2; kc++) {
          bf8_t bk = ldbf8(&KsC[krow * 64 + (((kc * 4 + quad) ^ fk) * 8)]);
          sc[0][ctl] = MFMA16(bk, aq[0][kc], sc[0][ctl]);
          sc[1][ctl] = MFMA16(bk, aq[1][kc], sc[1][ctl]);
        }
      }
      __builtin_amdgcn_s_setprio(0);

      // exp2 -> cvt_pk: words land directly in PV A-fragment order.
      bf8_t ap[2];
#pragma unroll
      for (int t = 0; t < 2; t++) {
        u32x4_t t4;
        t4[0] = pkbf(__builtin_amdgcn_exp2f(sc[t][0][0]),
                     __builtin_amdgcn_exp2f(sc[t][0][1]));
        t4[1] = pkbf(__builtin_amdgcn_exp2f(sc[t][0][2]),
                     __builtin_amdgcn_exp2f(sc[t][0][3]));
        t4[2] = pkbf(__builtin_amdgcn_exp2f(sc[t][1][0]),
                     __builtin_amdgcn_exp2f(sc[t][1][1]));
        t4[3] = pkbf(__builtin_amdgcn_exp2f(sc[t][1][2]),
                     __builtin_amdgcn_exp2f(sc[t][1][3]));
        ap[t] = __builtin_bit_cast(bf8_t, t4);
      }

      {
        __builtin_amdgcn_s_setprio(1);
        lacc[0] = MFMA16(ap[0], vones, lacc[0]);
        lacc[1] = MFMA16(ap[1], vones, lacc[1]);
        int gk = hh * 4 + quad;
#pragma unroll
        for (int cv = 0; cv < 4; cv++) {
          int vr = cv * 16 + col;
          bf8_t bv = ldbf8(&VsC[vr * 64 + ((gk ^ (vr & 7)) * 8)]);
          o[0][cv] = MFMA16(ap[0], bv, o[0][cv]);
          o[1][cv] = MFMA16(ap[1], bv, o[1][cv]);
        }
        __builtin_amdgcn_s_setprio(0);
      }
    }
  };

  stage(0, 0);
#pragma unroll 2
  for (int kt = 0; kt < S_ / 64 - 1; kt++) {
    stage(kt + 1, (kt + 1) & 1);
    asm volatile("s_waitcnt vmcnt(4)" ::: "memory");
    __builtin_amdgcn_s_barrier();
    compute_tile(&Ks[kt & 1][0], &Vs[kt & 1][0]);
    __builtin_amdgcn_s_barrier();
  }
  asm volatile("s_waitcnt vmcnt(0)" ::: "memory");
  __builtin_amdgcn_s_barrier();
  compute_tile(&Ks[1][0], &Vs[1][0]);

  const int b = bh >> 4, h = bh & 15;
#pragma unroll
  for (int t = 0; t < 2; t++) {
    float linv[4];
#pragma unroll
    for (int r = 0; r < 4; r++)
      linv[r] = 1.0f / lacc[t][r];
#pragma unroll
    for (int cv = 0; cv < 4; cv++)
#pragma unroll
      for (int r = 0; r < 4; r++) {
        float v = o[t][cv][r] * linv[r];
        int s = qt * 128 + w * 32 + t * 16 + quad * 4 + r;
        int dcol = h * 64 + cv * 16 + col;
        Cc[((size_t)b * S_ + s) * D_ + dcol] = f2bf(v);
      }
  }
}

// ---------------- stage 3: output projection ----------------
// f32 epilogue via 32x128 LDS tile -> 16B/lane coalesced stores.

__global__ __launch_bounds__(256, 3) void gemm_out(const unsigned short* __restrict__ A,
    const unsigned short* __restrict__ Bt, float* __restrict__ Out)
{
  __shared__ __align__(16) unsigned short As[128 * 32];
  __shared__ __align__(16) unsigned short Bs[128 * 32];
  __shared__ __align__(16) float Cf[32 * 132];            // 16.9 KB epilogue tile
  f4_t acc[4][4] = {};
  const int bm = blockIdx.y * 128, bn = blockIdx.x * 128;
  gemm_core(A, Bt, As, Bs, bm, bn, acc);

  const int tid = threadIdx.x, w = tid >> 6, lane = tid & 63;
  const int quad = lane >> 4, col = lane & 15;
  const int wn = (w & 1) * 64;
#pragma unroll
  for (int p = 0; p < 4; p++) {
    __syncthreads();
    if ((w >> 1) == (p >> 1)) {
#pragma unroll
      for (int mi = 0; mi < 2; mi++) {
        int mt = 2 * (p & 1) + mi;
        int lr0 = mi * 16 + quad * 4;
#pragma unroll
        for (int nt = 0; nt < 4; nt++) {
          int n = wn + nt * 16 + col;
#pragma unroll
          for (int r = 0; r < 4; r++)
            Cf[(lr0 + r) * 132 + n] = acc[mt][nt][r];
        }
      }
    }
    __syncthreads();
#pragma unroll
    for (int it = 0; it < 4; it++) {
      int u = it * 256 + tid;                         // 0..1023
      int lr = u >> 5, kk4 = u & 31;
      f4_t v = *(const f4_t*)&Cf[lr * 132 + kk4 * 4];
      int g = bm + 32 * p + lr;
      *(f4_t*)&Out[(size_t)g * D_ + bn + kk4 * 4] = v;
    }
  }
}

// ---------------- launch ----------------

extern "C" void kernel_launch(void* const* d_in, const int* in_sizes, int n_in,
                              void* d_out, int out_size, void* d_ws, size_t ws_size,
                              hipStream_t stream) {
  const float* x  = (const float*)d_in[0];
  const float* Wq = (const float*)d_in[1];
  const float* Wk = (const float*)d_in[2];
  const float* Wv = (const float*)d_in[3];
  const float* Wo = (const float*)d_in[4];
  float* out = (float*)d_out;

  char* ws = (char*)d_ws;
  size_t off = 0;
  auto alloc = [&](size_t bytes) -> void* {
    void* p = ws + off;
    off += (bytes + 255) & ~(size_t)255;
    return p;
  };
  unsigned short* xb   = (unsigned short*)alloc((size_t)M_ * D_ * 2);       // 16 MB
  unsigned short* Wcat = (unsigned short*)alloc((size_t)3 * D_ * D_ * 2);   // 6 MB
  unsigned short* Wot  = (unsigned short*)alloc((size_t)D_ * D_ * 2);       // 2 MB
  unsigned short* Qb   = (unsigned short*)alloc((size_t)B_ * H_ * S_ * DH_ * 2); // 16 MB
  unsigned short* Kb   = (unsigned short*)alloc((size_t)B_ * H_ * S_ * DH_ * 2); // 16 MB
  unsigned short* Vtb  = (unsigned short*)alloc((size_t)B_ * H_ * S_ * DH_ * 2); // 16 MB
  unsigned short* Cc   = (unsigned short*)alloc((size_t)M_ * D_ * 2);       // 16 MB

  cvt_all<<<8640, 256, 0, stream>>>(x, Wq, Wk, Wv, Wo, xb, Wcat, Wot);
  gemm_qkv<<<dim3(3 * D_ / 128, M_ / 128), 256, 0, stream>>>(xb, Wcat, Qb, Kb, Vtb);
  flash_attn<<<dim3(B_ * H_, S_ / 128), 256, 0, stream>>>(Qb, Kb, Vtb, Cc);
  gemm_out<<<dim3(D_ / 128, M_ / 128), 256, 0, stream>>>(Cc, Wot, out);
}